// Round 8
// baseline (189.155 us; speedup 1.0000x reference)
//
#include <hip/hip_runtime.h>
#include <hip/hip_bf16.h>

// B=4, N=2048, D_MODEL=512, H=4, DK=64, DV=128. fp32 in/out, bf16 MFMA.
// Softmax over BATCH axis (4 values) -> in-register per lane.
// R8: (1) GEMMs: m97-style global_load_lds(16B) staging, unpadded stride-64
// LDS (R5's all-zero failure was the pk-bf16 atomic, not gl_lds: out was
// EXACTLY zero => AO=0 => atomics no-op'd). (2) attn: hoist all V-fragment
// loads before softmax+barrier (LDS caps occupancy at 2 WG/CU, VGPRs free).

typedef __attribute__((ext_vector_type(8))) short short8;   // 8 x bf16
typedef __attribute__((ext_vector_type(4))) float floatx4;  // MFMA 16x16 acc
typedef unsigned short u16;
typedef unsigned int u32;

#define MFMA16(a, b, c) __builtin_amdgcn_mfma_f32_16x16x32_bf16((a), (b), (c), 0, 0, 0)

__device__ __forceinline__ u16 f2bf(float f) {
    union { float f; unsigned u; } v; v.f = f;
    unsigned r = v.u + 0x7fffu + ((v.u >> 16) & 1u);  // RNE
    return (u16)(r >> 16);
}

__device__ __forceinline__ float bf2f(u16 b) {
    union { unsigned u; float f; } v; v.u = ((u32)b) << 16;
    return v.f;
}

__device__ __forceinline__ u32 pk2bf(float a, float b) {
#if __has_builtin(__builtin_amdgcn_cvt_pk_bf16_f32)
    typedef __attribute__((ext_vector_type(2))) __bf16 bf16x2;
    union { bf16x2 v; u32 u; } c;
    c.v = __builtin_amdgcn_cvt_pk_bf16_f32(a, b);
    return c.u;
#else
    return (u32)f2bf(a) | ((u32)f2bf(b) << 16);
#endif
}

__device__ __forceinline__ float ex2(float x) {
#if __has_builtin(__builtin_amdgcn_exp2f)
    return __builtin_amdgcn_exp2f(x);
#else
    return exp2f(x);
#endif
}

// async global->LDS, 16B per lane. LDS dest must be wave-uniform base;
// lane lands at base + lane*16B (m97-verified pattern).
__device__ __forceinline__ void gload_lds16(const u16* g, u16* l) {
    __builtin_amdgcn_global_load_lds(
        (const __attribute__((address_space(1))) void*)(const void*)g,
        (__attribute__((address_space(3))) void*)(void*)l, 16, 0, 0);
}

// ---------------- cast fp32 -> bf16 (X) ----------------
__global__ __launch_bounds__(256) void cast_x_kernel(const float* __restrict__ x,
                                                     u16* __restrict__ xb) {
    int i = blockIdx.x * 256 + threadIdx.x;  // 1,048,576 float4 groups exactly
    float4 v = ((const float4*)x)[i];
    ushort4 o;
    o.x = f2bf(v.x); o.y = f2bf(v.y); o.z = f2bf(v.z); o.w = f2bf(v.w);
    ((ushort4*)xb)[i] = o;
}

// ---- weights: fp32 [K][N] -> bf16 transposed [N][K]; [Wq|Wk|Wv] fused ----
// Q columns pre-scaled by 0.125*log2(e) so S arrives in log2 domain.
__global__ __launch_bounds__(256) void prep_w_kernel(
    const float* __restrict__ Wq, const float* __restrict__ Wk,
    const float* __restrict__ Wv, const float* __restrict__ Wo,
    u16* __restrict__ WallT, u16* __restrict__ WoT) {
    int i = blockIdx.x * 256 + threadIdx.x;  // 1024*512 + 512*512 = 786432
    if (i < 524288) {
        int n = i >> 9, k = i & 511;
        float v;
        if (n < 256)      v = Wq[k * 256 + n] * 0.18033688011f;
        else if (n < 512) v = Wk[k * 256 + (n - 256)];
        else              v = Wv[k * 512 + (n - 512)];
        WallT[i] = f2bf(v);
    } else {
        int j = i - 524288;
        int n = j >> 9, k = j & 511;
        WoT[j] = f2bf(Wo[k * 512 + n]);
    }
}

// ------- GEMM: C[M][N] = A[M][K] * BT[N][K]^T, 128x128 tile, gl_lds -------
// 4 waves 2x2, each wave 64x64 (4x4 c-frags). BK=64, LDS stride 64 (unpadded
// -- required by global_load_lds lane ordering; m97 structure).
// mode 1: fp32 plain store (ldc). mode 2: QKV routing by nbase:
//   nbase<256 -> Qp packed; <512 -> Kp packed; else Vp packed.
// Qp: ((((b*4+h)*128+qs)*2+ki)*64+lane)*8+j
// Kp: ((((((b*4+h)*32+kt)*2+half)*2+nj)*2+ki)*64+lane)*8+j
// Vp: ((((((b*4+h)*32+kt)*2+half)*4+ni)*2+w)*64+lane)*8+j
__global__ __launch_bounds__(256) void gemm_kernel(
    const u16* __restrict__ A, const u16* __restrict__ BT,
    float* __restrict__ Cf, u16* __restrict__ Qp, u16* __restrict__ Kp,
    u16* __restrict__ Vp, int Kdim, int ldc, int mode) {
    __shared__ u16 Asl[128 * 64];
    __shared__ u16 Bsl[128 * 64];
    const int tid = threadIdx.x;
    const int mbase = blockIdx.y * 128;
    const int nbase = blockIdx.x * 128;
    const int wave = tid >> 6, lane = tid & 63;
    const int wm = wave >> 1, wn = wave & 1;
    const int lq = lane & 15, quad = lane >> 4;

    // staging: wave covers rows [wave*32, wave*32+32), 4 issues of 8 rows;
    // lane -> row lane/8, col (lane%8)*8 (matches LDS lane*16B scatter).
    const u16* gA = A + (size_t)(mbase + wave * 32 + (lane >> 3)) * Kdim + (lane & 7) * 8;
    const u16* gB = BT + (size_t)(nbase + wave * 32 + (lane >> 3)) * Kdim + (lane & 7) * 8;
    u16* lA = &Asl[(wave * 32) * 64];
    u16* lB = &Bsl[(wave * 32) * 64];

    const floatx4 z4 = {0.f, 0.f, 0.f, 0.f};
    floatx4 acc[4][4];
#pragma unroll
    for (int i = 0; i < 4; i++)
#pragma unroll
        for (int j = 0; j < 4; j++) acc[i][j] = z4;

    const int nk = Kdim >> 6;
    for (int kk = 0; kk < nk; kk++) {
        const int kb = kk << 6;
        if (kk) __syncthreads();
#pragma unroll
        for (int i = 0; i < 4; i++) {
            gload_lds16(gA + kb + (size_t)(i * 8) * Kdim, lA + (i * 8) * 64);
            gload_lds16(gB + kb + (size_t)(i * 8) * Kdim, lB + (i * 8) * 64);
        }
        __syncthreads();  // compiler drains vmcnt before barrier
#pragma unroll
        for (int ki = 0; ki < 2; ki++) {
            short8 af[4], bf[4];
#pragma unroll
            for (int mi = 0; mi < 4; mi++)
                af[mi] = *(const short8*)&Asl[(wm * 64 + mi * 16 + lq) * 64 + ki * 32 + quad * 8];
#pragma unroll
            for (int ni = 0; ni < 4; ni++)
                bf[ni] = *(const short8*)&Bsl[(wn * 64 + ni * 16 + lq) * 64 + ki * 32 + quad * 8];
#pragma unroll
            for (int mi = 0; mi < 4; mi++)
#pragma unroll
                for (int ni = 0; ni < 4; ni++)
                    acc[mi][ni] = MFMA16(af[mi], bf[ni], acc[mi][ni]);
        }
    }
    // epilogue: C/D layout col=lane&15, row=quad*4+reg (verified m89/m91)
    if (mode == 1) {
#pragma unroll
        for (int mi = 0; mi < 4; mi++)
#pragma unroll
            for (int ni = 0; ni < 4; ni++)
#pragma unroll
                for (int r = 0; r < 4; r++)
                    Cf[(size_t)(mbase + wm * 64 + mi * 16 + quad * 4 + r) * ldc +
                       (nbase + wn * 64 + ni * 16 + lq)] = acc[mi][ni][r];
    } else if (nbase < 256) {  // Q-packed
#pragma unroll
        for (int mi = 0; mi < 4; mi++)
#pragma unroll
            for (int ni = 0; ni < 4; ni++) {
                int col = nbase + wn * 64 + ni * 16 + lq;        // [0,256)
                int hq = col >> 6, dkc = col & 63;
                int ki = dkc >> 5, qd = (dkc >> 3) & 3, jq = dkc & 7;
#pragma unroll
                for (int r = 0; r < 4; r++) {
                    int row = mbase + wm * 64 + mi * 16 + quad * 4 + r;
                    int b = row >> 11, q = row & 2047;
                    int qs = q >> 4, lqq = q & 15;
                    Qp[((size_t)((((b * 4 + hq) * 128 + qs) * 2 + ki) * 64 +
                                 (qd * 16 + lqq)) << 3) + jq] = f2bf(acc[mi][ni][r]);
                }
            }
    } else if (nbase < 512) {  // K-packed
#pragma unroll
        for (int mi = 0; mi < 4; mi++)
#pragma unroll
            for (int ni = 0; ni < 4; ni++) {
                int colk = nbase + wn * 64 + ni * 16 + lq - 256;  // [0,256)
                int h = colk >> 6, dkc = colk & 63;
                int ki = dkc >> 5, quadk = (dkc >> 3) & 3, j = dkc & 7;
#pragma unroll
                for (int r = 0; r < 4; r++) {
                    int row = mbase + wm * 64 + mi * 16 + quad * 4 + r;
                    int b = row >> 11, key = row & 2047;
                    int kt = key >> 6, r6 = key & 63;
                    int half = r6 >> 5, r5 = r6 & 31;
                    int lqk = r5 >> 1, nj = r5 & 1;
                    Kp[((size_t)((((((b * 4 + h) * 32 + kt) * 2 + half) * 2 + nj)
                                  * 2 + ki) * 64 + (quadk * 16 + lqk)) << 3) + j] =
                        f2bf(acc[mi][ni][r]);
                }
            }
    } else {  // V-packed: row=token -> (b,key), col-512 = dv
#pragma unroll
        for (int mi = 0; mi < 4; mi++)
#pragma unroll
            for (int ni = 0; ni < 4; ni++) {
                int dv = nbase + wn * 64 + ni * 16 + lq - 512;    // [0,512)
                int h = dv >> 7, r7 = dv & 127;
                int half = r7 >> 6, r6v = r7 & 63;
                int niv = r6v >> 4, lqv = r6v & 15;
#pragma unroll
                for (int r = 0; r < 4; r++) {
                    int row = mbase + wm * 64 + mi * 16 + quad * 4 + r;
                    int b = row >> 11, key = row & 2047;
                    int kt = key >> 6, r6 = key & 63;
                    int w = r6 >> 5, r5 = r6 & 31;
                    int quadv = r5 >> 3, jv = r5 & 7;
                    Vp[((size_t)((((((b * 4 + h) * 32 + kt) * 2 + half) * 4 + niv)
                                  * 2 + w) * 64 + (quadv * 16 + lqv)) << 3) + jv] =
                        f2bf(acc[mi][ni][r]);
                }
            }
    }
}

// ---------------- fused attention: q64-tile, 8 waves, shared-P -----------
// Grid: 512 WGs = h(bx&3) x chunk((bx>>2)&3) x qtile(bx>>4, 32 of 64 rows).
// Block: 8 waves; wave = (mi = wave&3 -> q-sub16, half = wave>>2).
// Per kt: S+softmax for (mi, key-half); V fragment loads hoisted BEFORE the
// softmax+barrier (independent of P) to hide L2 latency; P in per-mi
// double-buffered XOR-swizzled LDS; 1 barrier; PV from full 64-key P.
__global__ __launch_bounds__(512) void attn_kernel(const u16* __restrict__ Qp,
                                                   const u16* __restrict__ Kp,
                                                   const u16* __restrict__ Vp,
                                                   u16* __restrict__ Pp) {
    __shared__ u16 pl[2 * 4 * 4096];  // [buf][mi][b*16+q][64], 64 KB exactly
    const int bx = blockIdx.x;
    const int h = bx & 3;
    const int ck = (bx >> 2) & 3;
    const int qt = bx >> 4;                     // [0,32)
    const int tid = threadIdx.x;
    const int wave = tid >> 6, lane = tid & 63;
    const int mi = wave & 3, half = wave >> 2;  // S key-half / PV dv-half
    const int lq = lane & 15, quad = lane >> 4;
    const int q0 = qt * 64 + mi * 16;
    const int qs = qt * 4 + mi;                 // q0 >> 4

    // Q a-frags (fragment-packed, coalesced): A[m=lane&15][k=quad*8+j]
    short8 aq[4][2];
#pragma unroll
    for (int b = 0; b < 4; b++)
#pragma unroll
        for (int ki = 0; ki < 2; ki++)
            aq[b][ki] = *(const short8*)&Qp[
                ((size_t)((((b * 4 + h) * 128 + qs) * 2 + ki) * 64 + lane) << 3)];

    const floatx4 z4 = {0.f, 0.f, 0.f, 0.f};
    floatx4 oacc[4][4];
#pragma unroll
    for (int b = 0; b < 4; b++)
#pragma unroll
        for (int ni = 0; ni < 4; ni++) oacc[b][ni] = z4;

    for (int kt = ck * 8; kt < ck * 8 + 8; kt++) {
        u16* plb = &pl[((kt & 1) * 4 + mi) * 4096];
        // ---- S (log2 domain) for this wave's 32 keys, all 4 batches ----
        floatx4 s[4][2];
#pragma unroll
        for (int b = 0; b < 4; b++) {
            const u16* kb = Kp +
                ((size_t)((((b * 4 + h) * 32 + kt) * 2 + half) * 2) << 10) +
                lane * 8;
#pragma unroll
            for (int nj = 0; nj < 2; nj++) {
                s[b][nj] = z4;
#pragma unroll
                for (int ki = 0; ki < 2; ki++)
                    s[b][nj] = MFMA16(aq[b][ki],
                                      *(const short8*)(kb + (nj * 2 + ki) * 512),
                                      s[b][nj]);
            }
        }
        // ---- hoisted V loads (independent of P; overlap softmax+barrier)
        short8 vf[4][8];
#pragma unroll
        for (int b = 0; b < 4; b++) {
            const u16* vb = Vp +
                ((size_t)((((b * 4 + h) * 32 + kt) * 2 + half) * 8) << 9) +
                lane * 8;
#pragma unroll
            for (int t = 0; t < 8; t++)
                vf[b][t] = *(const short8*)(vb + t * 512);
        }
        // ---- softmax over batch: e = 2^S (no max-sub; |S| small) ----
        // lane holds S[q=quad*4+r][key = half*32 + 2*lq + nj]
#pragma unroll
        for (int r = 0; r < 4; r++) {
            float e0a = ex2(s[0][0][r]), e0b = ex2(s[0][1][r]);
            float e1a = ex2(s[1][0][r]), e1b = ex2(s[1][1][r]);
            float e2a = ex2(s[2][0][r]), e2b = ex2(s[2][1][r]);
            float e3a = ex2(s[3][0][r]), e3b = ex2(s[3][1][r]);
            float ia = __builtin_amdgcn_rcpf(e0a + e1a + e2a + e3a);
            float ib = __builtin_amdgcn_rcpf(e0b + e1b + e2b + e3b);
            int q = quad * 4 + r;
            int col = (half * 32 + 2 * lq) ^ ((q & 7) * 8);  // XOR swizzle
            *(u32*)&plb[(0 * 16 + q) * 64 + col] = pk2bf(e0a * ia, e0b * ib);
            *(u32*)&plb[(1 * 16 + q) * 64 + col] = pk2bf(e1a * ia, e1b * ib);
            *(u32*)&plb[(2 * 16 + q) * 64 + col] = pk2bf(e2a * ia, e2b * ib);
            *(u32*)&plb[(3 * 16 + q) * 64 + col] = pk2bf(e3a * ia, e3b * ib);
        }
        __syncthreads();  // P complete for both key-halves of this buffer
        // ---- O += P V : full 64 keys, this wave's dv-half ----
        const int sw = (lq & 7) * 8;
#pragma unroll
        for (int b = 0; b < 4; b++) {
            short8 ap0 = *(const short8*)&plb[(b * 16 + lq) * 64 + ((quad * 8) ^ sw)];
            short8 ap1 = *(const short8*)&plb[(b * 16 + lq) * 64 + ((32 + quad * 8) ^ sw)];
#pragma unroll
            for (int ni = 0; ni < 4; ni++) {
                oacc[b][ni] = MFMA16(ap0, vf[b][ni * 2 + 0], oacc[b][ni]);
                oacc[b][ni] = MFMA16(ap1, vf[b][ni * 2 + 1], oacc[b][ni]);
            }
        }
        // next iteration writes the other buffer -> no second barrier
    }
    // ---- epilogue: plain bf16 stores to this chunk's partial buffer ----
    u16* Pc = Pp + (size_t)ck * (8192 * 512);
#pragma unroll
    for (int b = 0; b < 4; b++)
#pragma unroll
        for (int ni = 0; ni < 4; ni++)
#pragma unroll
            for (int r = 0; r < 4; r++)
                Pc[(size_t)(b * 2048 + q0 + quad * 4 + r) * 512 +
                   h * 128 + half * 64 + ni * 16 + lq] = f2bf(oacc[b][ni][r]);
}

// ---------------- reduce 4 bf16 partials in place (P0 += P1+P2+P3) --------
__global__ __launch_bounds__(256) void reduce4_kernel(u16* __restrict__ P) {
    const size_t S = (size_t)8192 * 512;
    size_t i = ((size_t)blockIdx.x * 256 + threadIdx.x) * 8;  // 2048 blocks
    short8 a = *(short8*)&P[i];
    short8 b = *(short8*)&P[i + S];
    short8 c = *(short8*)&P[i + 2 * S];
    short8 d = *(short8*)&P[i + 3 * S];
    short8 o;
#pragma unroll
    for (int j = 0; j < 8; j++) {
        float s = bf2f((u16)a[j]) + bf2f((u16)b[j]) +
                  bf2f((u16)c[j]) + bf2f((u16)d[j]);
        o[j] = (short)f2bf(s);
    }
    *(short8*)&P[i] = o;
}

extern "C" void kernel_launch(void* const* d_in, const int* in_sizes, int n_in,
                              void* d_out, int out_size, void* d_ws, size_t ws_size,
                              hipStream_t stream) {
    const float* x  = (const float*)d_in[0];
    const float* Wq = (const float*)d_in[1];
    const float* Wk = (const float*)d_in[2];
    const float* Wv = (const float*)d_in[3];
    const float* Wo = (const float*)d_in[4];
    float* out = (float*)d_out;

    // Workspace map (48.5 MB). Pp[0..4) partials occupy [0, 32MB); Xb (8MB)
    // and WallT (1MB) are OVERLAID at the start of that region -- both dead
    // before attn writes partials. P0 doubles as AO after reduce4.
    char* ws = (char*)d_ws;
    u16* Pp    = (u16*)ws;                                   // 4 x 8MB bf16
    u16* Xb    = (u16*)ws;                                   // overlay [0,8MB)
    u16* WallT = (u16*)(ws + (size_t)8 * 1024 * 1024);       // overlay [8,9MB)
    char* tail = ws + (size_t)32 * 1024 * 1024;
    u16* WoT   = (u16*)tail; tail += (size_t)512 * 512 * 2;  // 0.5MB
    u16* Qp    = (u16*)tail; tail += (size_t)8192 * 256 * 2; // 4MB
    u16* Kp    = (u16*)tail; tail += (size_t)8192 * 256 * 2; // 4MB
    u16* Vp    = (u16*)tail; tail += (size_t)8192 * 512 * 2; // 8MB

    cast_x_kernel<<<4096, 256, 0, stream>>>(x, Xb);
    prep_w_kernel<<<3072, 256, 0, stream>>>(Wq, Wk, Wv, Wo, WallT, WoT);
    // QKV = X @ [Wq|Wk|Wv] : [8192,1024] -> Qp/Kp/Vp packed (512 blocks)
    gemm_kernel<<<dim3(8, 64), 256, 0, stream>>>(Xb, WallT, nullptr,
                                                 Qp, Kp, Vp, 512, 0, 2);
    attn_kernel<<<512, 512, 0, stream>>>(Qp, Kp, Vp, Pp);
    reduce4_kernel<<<2048, 256, 0, stream>>>(Pp);
    // out = AO(=P0) @ Wo : fp32 (256 blocks)
    gemm_kernel<<<dim3(4, 64), 256, 0, stream>>>(Pp, WoT, out,
                                                 nullptr, nullptr, nullptr,
                                                 512, 512, 1);
}

// Round 9
// 172.227 us; speedup vs baseline: 1.0983x; 1.0983x over previous
//
#include <hip/hip_runtime.h>
#include <hip/hip_bf16.h>

// B=4, N=2048, D_MODEL=512, H=4, DK=64, DV=128. fp32 in/out, bf16 MFMA.
// Softmax over BATCH axis (4 values) -> in-register per lane.
// R9: (1) attn PV restructure: wave = dv-16-slice (dq), computes O[all 4
// mi][16 dv] reading shared P from LDS -> V load duplication 4x -> 1x
// (issued L2 traffic 1.57 GB -> 0.79 GB). (2) GEMM mode-2 epilogue via LDS
// round-trip: C-tile -> LDS (V-tiles transposed), then 32 coalesced 1KB
// wave-line stores (was 64 scattered 2B stores/thread).

typedef __attribute__((ext_vector_type(8))) short short8;   // 8 x bf16
typedef __attribute__((ext_vector_type(4))) float floatx4;  // MFMA 16x16 acc
typedef unsigned short u16;
typedef unsigned int u32;

#define MFMA16(a, b, c) __builtin_amdgcn_mfma_f32_16x16x32_bf16((a), (b), (c), 0, 0, 0)

__device__ __forceinline__ u16 f2bf(float f) {
    union { float f; unsigned u; } v; v.f = f;
    unsigned r = v.u + 0x7fffu + ((v.u >> 16) & 1u);  // RNE
    return (u16)(r >> 16);
}

__device__ __forceinline__ float bf2f(u16 b) {
    union { unsigned u; float f; } v; v.u = ((u32)b) << 16;
    return v.f;
}

__device__ __forceinline__ u32 pk2bf(float a, float b) {
#if __has_builtin(__builtin_amdgcn_cvt_pk_bf16_f32)
    typedef __attribute__((ext_vector_type(2))) __bf16 bf16x2;
    union { bf16x2 v; u32 u; } c;
    c.v = __builtin_amdgcn_cvt_pk_bf16_f32(a, b);
    return c.u;
#else
    return (u32)f2bf(a) | ((u32)f2bf(b) << 16);
#endif
}

__device__ __forceinline__ float ex2(float x) {
#if __has_builtin(__builtin_amdgcn_exp2f)
    return __builtin_amdgcn_exp2f(x);
#else
    return exp2f(x);
#endif
}

// async global->LDS, 16B per lane. LDS dest wave-uniform base + lane*16B.
__device__ __forceinline__ void gload_lds16(const u16* g, u16* l) {
    __builtin_amdgcn_global_load_lds(
        (const __attribute__((address_space(1))) void*)(const void*)g,
        (__attribute__((address_space(3))) void*)(void*)l, 16, 0, 0);
}

// ---------------- cast fp32 -> bf16 (X) ----------------
__global__ __launch_bounds__(256) void cast_x_kernel(const float* __restrict__ x,
                                                     u16* __restrict__ xb) {
    int i = blockIdx.x * 256 + threadIdx.x;  // 1,048,576 float4 groups exactly
    float4 v = ((const float4*)x)[i];
    ushort4 o;
    o.x = f2bf(v.x); o.y = f2bf(v.y); o.z = f2bf(v.z); o.w = f2bf(v.w);
    ((ushort4*)xb)[i] = o;
}

// ---- weights: fp32 [K][N] -> bf16 transposed [N][K]; [Wq|Wk|Wv] fused ----
// Q columns pre-scaled by 0.125*log2(e) so S arrives in log2 domain.
__global__ __launch_bounds__(256) void prep_w_kernel(
    const float* __restrict__ Wq, const float* __restrict__ Wk,
    const float* __restrict__ Wv, const float* __restrict__ Wo,
    u16* __restrict__ WallT, u16* __restrict__ WoT) {
    int i = blockIdx.x * 256 + threadIdx.x;  // 1024*512 + 512*512 = 786432
    if (i < 524288) {
        int n = i >> 9, k = i & 511;
        float v;
        if (n < 256)      v = Wq[k * 256 + n] * 0.18033688011f;
        else if (n < 512) v = Wk[k * 256 + (n - 256)];
        else              v = Wv[k * 512 + (n - 512)];
        WallT[i] = f2bf(v);
    } else {
        int j = i - 524288;
        int n = j >> 9, k = j & 511;
        WoT[j] = f2bf(Wo[k * 512 + n]);
    }
}

// ------- GEMM: C[M][N] = A[M][K] * BT[N][K]^T, 128x128 tile, gl_lds -------
// 4 waves 2x2, each wave 64x64 (4x4 c-frags). BK=64, staging LDS stride 64.
// mode 1: fp32 plain store. mode 2: LDS-roundtrip epilogue, then coalesced
// 1KB wave-line stores into Qp/Kp/Vp packed layouts (tile type by nbase).
// Qp: ((((b*4+h)*128+qs)*2+ki)*64+lane)*8+j
// Kp: ((((((b*4+h)*32+kt)*2+half)*2+nj)*2+ki)*64+lane)*8+j
// Vp: ((((((b*4+h)*32+kt)*2+half)*4+ni)*2+w)*64+lane)*8+j
__global__ __launch_bounds__(256) void gemm_kernel(
    const u16* __restrict__ A, const u16* __restrict__ BT,
    float* __restrict__ Cf, u16* __restrict__ Qp, u16* __restrict__ Kp,
    u16* __restrict__ Vp, int Kdim, int ldc, int mode) {
    __shared__ u16 sm[16896];          // 33 KB; staging uses [0,16384)
    u16* Asl = sm;                      // 128x64, stride 64
    u16* Bsl = sm + 8192;               // 128x64, stride 64
    const int tid = threadIdx.x;
    const int mbase = blockIdx.y * 128;
    const int nbase = blockIdx.x * 128;
    const int wave = tid >> 6, lane = tid & 63;
    const int wm = wave >> 1, wn = wave & 1;
    const int lq = lane & 15, quad = lane >> 4;

    const u16* gA = A + (size_t)(mbase + wave * 32 + (lane >> 3)) * Kdim + (lane & 7) * 8;
    const u16* gB = BT + (size_t)(nbase + wave * 32 + (lane >> 3)) * Kdim + (lane & 7) * 8;
    u16* lA = &Asl[(wave * 32) * 64];
    u16* lB = &Bsl[(wave * 32) * 64];

    const floatx4 z4 = {0.f, 0.f, 0.f, 0.f};
    floatx4 acc[4][4];
#pragma unroll
    for (int i = 0; i < 4; i++)
#pragma unroll
        for (int j = 0; j < 4; j++) acc[i][j] = z4;

    const int nk = Kdim >> 6;
    for (int kk = 0; kk < nk; kk++) {
        const int kb = kk << 6;
        if (kk) __syncthreads();
#pragma unroll
        for (int i = 0; i < 4; i++) {
            gload_lds16(gA + kb + (size_t)(i * 8) * Kdim, lA + (i * 8) * 64);
            gload_lds16(gB + kb + (size_t)(i * 8) * Kdim, lB + (i * 8) * 64);
        }
        __syncthreads();
#pragma unroll
        for (int ki = 0; ki < 2; ki++) {
            short8 af[4], bf[4];
#pragma unroll
            for (int mi = 0; mi < 4; mi++)
                af[mi] = *(const short8*)&Asl[(wm * 64 + mi * 16 + lq) * 64 + ki * 32 + quad * 8];
#pragma unroll
            for (int ni = 0; ni < 4; ni++)
                bf[ni] = *(const short8*)&Bsl[(wn * 64 + ni * 16 + lq) * 64 + ki * 32 + quad * 8];
#pragma unroll
            for (int mi = 0; mi < 4; mi++)
#pragma unroll
                for (int ni = 0; ni < 4; ni++)
                    acc[mi][ni] = MFMA16(af[mi], bf[ni], acc[mi][ni]);
        }
    }
    // epilogue. C/D layout: col=lane&15 (ni*16+lq), row=quad*4+r (mi*16+..).
    if (mode == 1) {
#pragma unroll
        for (int mi = 0; mi < 4; mi++)
#pragma unroll
            for (int ni = 0; ni < 4; ni++)
#pragma unroll
                for (int r = 0; r < 4; r++)
                    Cf[(size_t)(mbase + wm * 64 + mi * 16 + quad * 4 + r) * ldc +
                       (nbase + wn * 64 + ni * 16 + lq)] = acc[mi][ni][r];
        return;
    }
    // ---- mode 2: LDS round-trip. Phase 1: C-tile -> sm (stride 132). ----
    __syncthreads();  // all K-loop LDS reads done before overwrite
    const bool vtile = (nbase >= 512);
#pragma unroll
    for (int mi = 0; mi < 4; mi++)
#pragma unroll
        for (int ni = 0; ni < 4; ni++) {
            int cl = wn * 64 + ni * 16 + lq;
#pragma unroll
            for (int r = 0; r < 4; r++) {
                int rl = wm * 64 + mi * 16 + quad * 4 + r;
                if (vtile) sm[cl * 132 + rl] = f2bf(acc[mi][ni][r]);  // transposed
                else       sm[rl * 132 + cl] = f2bf(acc[mi][ni][r]);
            }
        }
    __syncthreads();
    // ---- Phase 2: 32 coalesced 1KB wave-lines (8 per wave). ----
    const int b = mbase >> 11;
    const int keyb = mbase & 2047;           // tile-base token within batch
    if (nbase < 256) {                        // Q tile
        const int hq = nbase >> 6;           // nbase in {0,128}: h2 added below
        const int qs_base = keyb >> 4;
#pragma unroll
        for (int t = 0; t < 8; t++) {
            int l = wave * 8 + t;
            int qs2 = l >> 2, h2 = (l >> 1) & 1, ki = l & 1;
            int qd = lane >> 4, lqq = lane & 15;
            short8 v = *(const short8*)&sm[(qs2 * 16 + lqq) * 132 + h2 * 64 + ki * 32 + qd * 8];
            int h = hq + h2;
            size_t base = ((size_t)(((b * 4 + h) * 128 + (qs_base + qs2)) * 2 + ki) * 64 + lane) << 3;
            *(short8*)&Qp[base] = v;
        }
    } else if (nbase < 512) {                 // K tile
        const int hb = (nbase - 256) >> 6;   // {0,2}
        const int ktb = keyb >> 6;
#pragma unroll
        for (int t = 0; t < 8; t++) {
            int l = wave * 8 + t;
            int kt2 = l >> 4, hf = (l >> 3) & 1, nj = (l >> 2) & 1;
            int h2 = (l >> 1) & 1, ki = l & 1;
            int quadk = lane >> 4, lqk = lane & 15;
            short8 v = *(const short8*)&sm[(kt2 * 64 + hf * 32 + lqk * 2 + nj) * 132 +
                                           h2 * 64 + ki * 32 + quadk * 8];
            int h = hb + h2;
            size_t base = ((size_t)(((((b * 4 + h) * 32 + (ktb + kt2)) * 2 + hf) * 2 + nj)
                                    * 2 + ki) * 64 + lane) << 3;
            *(short8*)&Kp[base] = v;
        }
    } else {                                  // V tile (sm is transposed)
        const int h = (nbase - 512) >> 7;    // tile spans exactly one head
        const int ktb = keyb >> 6;
#pragma unroll
        for (int t = 0; t < 8; t++) {
            int l = wave * 8 + t;
            int kt2 = l >> 4, hf = (l >> 3) & 1, niv = (l >> 1) & 3, wv = l & 1;
            int quadv = lane >> 4, lqv = lane & 15;
            short8 v = *(const short8*)&sm[(hf * 64 + niv * 16 + lqv) * 132 +
                                           kt2 * 64 + wv * 32 + quadv * 8];
            size_t base = ((size_t)(((((b * 4 + h) * 32 + (ktb + kt2)) * 2 + hf) * 4 + niv)
                                    * 2 + wv) * 64 + lane) << 3;
            *(short8*)&Vp[base] = v;
        }
    }
}

// ---------------- fused attention: q64-tile, 8 waves, shared-P -----------
// Grid: 512 WGs = h(bx&3) x chunk((bx>>2)&3) x qtile(bx>>4, 32 of 64 rows).
// S phase: wave = (mi = wave&3, half = wave>>2) computes S+softmax for its
// (q-sub16, 32-key half); P -> per-mi double-buffered XOR-swizzled LDS.
// PV phase (R9): wave = dv-16-slice dq; computes O[all 4 mi][16 dv] reading
// all P regions from LDS -> V loads deduplicated (8 short8/wave/kt).
__global__ __launch_bounds__(512) void attn_kernel(const u16* __restrict__ Qp,
                                                   const u16* __restrict__ Kp,
                                                   const u16* __restrict__ Vp,
                                                   u16* __restrict__ Pp) {
    __shared__ u16 pl[2 * 4 * 4096];  // [buf][mi][b*16+q][64], 64 KB exactly
    const int bx = blockIdx.x;
    const int h = bx & 3;
    const int ck = (bx >> 2) & 3;
    const int qt = bx >> 4;                     // [0,32)
    const int tid = threadIdx.x;
    const int wave = tid >> 6, lane = tid & 63;
    const int mi = wave & 3, half = wave >> 2;  // S phase roles
    const int dq = wave;                        // PV phase: dv-16-slice
    const int half_v = dq >> 2, ni_v = dq & 3;
    const int lq = lane & 15, quad = lane >> 4;
    const int qs = qt * 4 + mi;

    // Q a-frags (fragment-packed, coalesced): A[m=lane&15][k=quad*8+j]
    short8 aq[4][2];
#pragma unroll
    for (int b = 0; b < 4; b++)
#pragma unroll
        for (int ki = 0; ki < 2; ki++)
            aq[b][ki] = *(const short8*)&Qp[
                ((size_t)((((b * 4 + h) * 128 + qs) * 2 + ki) * 64 + lane) << 3)];

    const floatx4 z4 = {0.f, 0.f, 0.f, 0.f};
    floatx4 oacc[4][4];  // [b][mi2] -- O rows mi2*16.., cols dq*16+lq
#pragma unroll
    for (int b = 0; b < 4; b++)
#pragma unroll
        for (int m2 = 0; m2 < 4; m2++) oacc[b][m2] = z4;

    for (int kt = ck * 8; kt < ck * 8 + 8; kt++) {
        u16* plb = &pl[((kt & 1) * 4 + mi) * 4096];
        u16* plbuf = &pl[(kt & 1) * 4 * 4096];
        // ---- S (log2 domain) for this wave's 32 keys, all 4 batches ----
        floatx4 s[4][2];
#pragma unroll
        for (int b = 0; b < 4; b++) {
            const u16* kb = Kp +
                ((size_t)((((b * 4 + h) * 32 + kt) * 2 + half) * 2) << 10) +
                lane * 8;
#pragma unroll
            for (int nj = 0; nj < 2; nj++) {
                s[b][nj] = z4;
#pragma unroll
                for (int ki = 0; ki < 2; ki++)
                    s[b][nj] = MFMA16(aq[b][ki],
                                      *(const short8*)(kb + (nj * 2 + ki) * 512),
                                      s[b][nj]);
            }
        }
        // ---- V loads for PV (dedup: this wave's dv-16 slice only) ----
        short8 vf[4][2];
#pragma unroll
        for (int b = 0; b < 4; b++) {
            const u16* vb = Vp +
                ((size_t)(((((b * 4 + h) * 32 + kt) * 2 + half_v) * 4 + ni_v) * 2) << 9) +
                lane * 8;
            vf[b][0] = *(const short8*)vb;
            vf[b][1] = *(const short8*)(vb + 512);
        }
        // ---- softmax over batch: e = 2^S (no max-sub; |S| small) ----
        // lane holds S[q=quad*4+r][key = half*32 + 2*lq + nj]
#pragma unroll
        for (int r = 0; r < 4; r++) {
            float e0a = ex2(s[0][0][r]), e0b = ex2(s[0][1][r]);
            float e1a = ex2(s[1][0][r]), e1b = ex2(s[1][1][r]);
            float e2a = ex2(s[2][0][r]), e2b = ex2(s[2][1][r]);
            float e3a = ex2(s[3][0][r]), e3b = ex2(s[3][1][r]);
            float ia = __builtin_amdgcn_rcpf(e0a + e1a + e2a + e3a);
            float ib = __builtin_amdgcn_rcpf(e0b + e1b + e2b + e3b);
            int q = quad * 4 + r;
            int col = (half * 32 + 2 * lq) ^ ((q & 7) * 8);  // XOR swizzle
            *(u32*)&plb[(0 * 16 + q) * 64 + col] = pk2bf(e0a * ia, e0b * ib);
            *(u32*)&plb[(1 * 16 + q) * 64 + col] = pk2bf(e1a * ia, e1b * ib);
            *(u32*)&plb[(2 * 16 + q) * 64 + col] = pk2bf(e2a * ia, e2b * ib);
            *(u32*)&plb[(3 * 16 + q) * 64 + col] = pk2bf(e3a * ia, e3b * ib);
        }
        __syncthreads();  // P complete for all mi regions of this buffer
        // ---- O += P V : all 4 mi, this wave's dv-16 slice ----
        const int sw = (lq & 7) * 8;
#pragma unroll
        for (int b = 0; b < 4; b++) {
#pragma unroll
            for (int m2 = 0; m2 < 4; m2++) {
                const u16* pm = plbuf + m2 * 4096;
                short8 ap0 = *(const short8*)&pm[(b * 16 + lq) * 64 + ((quad * 8) ^ sw)];
                short8 ap1 = *(const short8*)&pm[(b * 16 + lq) * 64 + ((32 + quad * 8) ^ sw)];
                oacc[b][m2] = MFMA16(ap0, vf[b][0], oacc[b][m2]);
                oacc[b][m2] = MFMA16(ap1, vf[b][1], oacc[b][m2]);
            }
        }
        // next iteration writes the other buffer -> no second barrier
    }
    // ---- epilogue: O[q=qt*64+m2*16+quad*4+r][dv=h*128+dq*16+lq] ----
    u16* Pc = Pp + (size_t)ck * (8192 * 512);
#pragma unroll
    for (int b = 0; b < 4; b++)
#pragma unroll
        for (int m2 = 0; m2 < 4; m2++)
#pragma unroll
            for (int r = 0; r < 4; r++)
                Pc[(size_t)(b * 2048 + qt * 64 + m2 * 16 + quad * 4 + r) * 512 +
                   h * 128 + dq * 16 + lq] = f2bf(oacc[b][m2][r]);
}

// ---------------- reduce 4 bf16 partials in place (P0 += P1+P2+P3) --------
__global__ __launch_bounds__(256) void reduce4_kernel(u16* __restrict__ P) {
    const size_t S = (size_t)8192 * 512;
    size_t i = ((size_t)blockIdx.x * 256 + threadIdx.x) * 8;  // 2048 blocks
    short8 a = *(short8*)&P[i];
    short8 b = *(short8*)&P[i + S];
    short8 c = *(short8*)&P[i + 2 * S];
    short8 d = *(short8*)&P[i + 3 * S];
    short8 o;
#pragma unroll
    for (int j = 0; j < 8; j++) {
        float s = bf2f((u16)a[j]) + bf2f((u16)b[j]) +
                  bf2f((u16)c[j]) + bf2f((u16)d[j]);
        o[j] = (short)f2bf(s);
    }
    *(short8*)&P[i] = o;
}

extern "C" void kernel_launch(void* const* d_in, const int* in_sizes, int n_in,
                              void* d_out, int out_size, void* d_ws, size_t ws_size,
                              hipStream_t stream) {
    const float* x  = (const float*)d_in[0];
    const float* Wq = (const float*)d_in[1];
    const float* Wk = (const float*)d_in[2];
    const float* Wv = (const float*)d_in[3];
    const float* Wo = (const float*)d_in[4];
    float* out = (float*)d_out;

    // Workspace map (48.5 MB). Pp[0..4) partials occupy [0, 32MB); Xb (8MB)
    // and WallT (1MB) are OVERLAID at the start -- both dead before attn
    // writes partials. P0 doubles as AO after reduce4.
    char* ws = (char*)d_ws;
    u16* Pp    = (u16*)ws;                                   // 4 x 8MB bf16
    u16* Xb    = (u16*)ws;                                   // overlay [0,8MB)
    u16* WallT = (u16*)(ws + (size_t)8 * 1024 * 1024);       // overlay [8,9MB)
    char* tail = ws + (size_t)32 * 1024 * 1024;
    u16* WoT   = (u16*)tail; tail += (size_t)512 * 512 * 2;  // 0.5MB
    u16* Qp    = (u16*)tail; tail += (size_t)8192 * 256 * 2; // 4MB
    u16* Kp    = (u16*)tail; tail += (size_t)8192 * 256 * 2; // 4MB
    u16* Vp    = (u16*)tail; tail += (size_t)8192 * 512 * 2; // 8MB

    cast_x_kernel<<<4096, 256, 0, stream>>>(x, Xb);
    prep_w_kernel<<<3072, 256, 0, stream>>>(Wq, Wk, Wv, Wo, WallT, WoT);
    // QKV = X @ [Wq|Wk|Wv] : [8192,1024] -> Qp/Kp/Vp packed (512 blocks)
    gemm_kernel<<<dim3(8, 64), 256, 0, stream>>>(Xb, WallT, nullptr,
                                                 Qp, Kp, Vp, 512, 0, 2);
    attn_kernel<<<512, 512, 0, stream>>>(Qp, Kp, Vp, Pp);
    reduce4_kernel<<<2048, 256, 0, stream>>>(Pp);
    // out = AO(=P0) @ Wo : fp32 (256 blocks)
    gemm_kernel<<<dim3(4, 64), 256, 0, stream>>>(Pp, WoT, out,
                                                 nullptr, nullptr, nullptr,
                                                 512, 512, 1);
}

// Round 10
// 166.679 us; speedup vs baseline: 1.1348x; 1.0333x over previous
//
#include <hip/hip_runtime.h>
#include <hip/hip_bf16.h>

// B=4, N=2048, D_MODEL=512, H=4, DK=64, DV=128. fp32 in/out, bf16 MFMA.
// Softmax over BATCH axis (4 values) -> in-register per lane.
// R10: (1) QKV GEMM 512-thr (8 waves, 2m x 4n of 64x32) -> 16 waves/CU
// (was 8). (2) out-GEMM: separate 64x128-tile 512-thr kernel, grid 512 ->
// 16 waves/CU (was 4). (3) cast_x + prep_w merged (-1 launch).
// attn unchanged from R9 (VGPR-capped at 16 waves/CU; already saturated).

typedef __attribute__((ext_vector_type(8))) short short8;   // 8 x bf16
typedef __attribute__((ext_vector_type(4))) float floatx4;  // MFMA 16x16 acc
typedef unsigned short u16;
typedef unsigned int u32;

#define MFMA16(a, b, c) __builtin_amdgcn_mfma_f32_16x16x32_bf16((a), (b), (c), 0, 0, 0)

__device__ __forceinline__ u16 f2bf(float f) {
    union { float f; unsigned u; } v; v.f = f;
    unsigned r = v.u + 0x7fffu + ((v.u >> 16) & 1u);  // RNE
    return (u16)(r >> 16);
}

__device__ __forceinline__ float bf2f(u16 b) {
    union { unsigned u; float f; } v; v.u = ((u32)b) << 16;
    return v.f;
}

__device__ __forceinline__ u32 pk2bf(float a, float b) {
#if __has_builtin(__builtin_amdgcn_cvt_pk_bf16_f32)
    typedef __attribute__((ext_vector_type(2))) __bf16 bf16x2;
    union { bf16x2 v; u32 u; } c;
    c.v = __builtin_amdgcn_cvt_pk_bf16_f32(a, b);
    return c.u;
#else
    return (u32)f2bf(a) | ((u32)f2bf(b) << 16);
#endif
}

__device__ __forceinline__ float ex2(float x) {
#if __has_builtin(__builtin_amdgcn_exp2f)
    return __builtin_amdgcn_exp2f(x);
#else
    return exp2f(x);
#endif
}

// async global->LDS, 16B per lane. LDS dest wave-uniform base + lane*16B.
__device__ __forceinline__ void gload_lds16(const u16* g, u16* l) {
    __builtin_amdgcn_global_load_lds(
        (const __attribute__((address_space(1))) void*)(const void*)g,
        (__attribute__((address_space(3))) void*)(void*)l, 16, 0, 0);
}

// ------- merged prep: cast X (blocks [0,4096)) + weights (blocks >=4096) ---
// Q columns pre-scaled by 0.125*log2(e) so S arrives in log2 domain.
__global__ __launch_bounds__(256) void prep_all_kernel(
    const float* __restrict__ x, u16* __restrict__ xb,
    const float* __restrict__ Wq, const float* __restrict__ Wk,
    const float* __restrict__ Wv, const float* __restrict__ Wo,
    u16* __restrict__ WallT, u16* __restrict__ WoT) {
    int bid = blockIdx.x;
    if (bid < 4096) {
        int i = bid * 256 + threadIdx.x;  // 1,048,576 float4 groups exactly
        float4 v = ((const float4*)x)[i];
        ushort4 o;
        o.x = f2bf(v.x); o.y = f2bf(v.y); o.z = f2bf(v.z); o.w = f2bf(v.w);
        ((ushort4*)xb)[i] = o;
        return;
    }
    int i = (bid - 4096) * 256 + threadIdx.x;  // 786432 exactly (3072 blocks)
    if (i < 524288) {
        int n = i >> 9, k = i & 511;
        float v;
        if (n < 256)      v = Wq[k * 256 + n] * 0.18033688011f;
        else if (n < 512) v = Wk[k * 256 + (n - 256)];
        else              v = Wv[k * 512 + (n - 512)];
        WallT[i] = f2bf(v);
    } else {
        int j = i - 524288;
        int n = j >> 9, k = j & 511;
        WoT[j] = f2bf(Wo[k * 512 + n]);
    }
}

// ------- QKV GEMM: C[M][N] = A[M][K]*BT[N][K]^T, 128x128 tile, 512 thr ----
// 8 waves as 2m x 4n, each wave 64x32 (4x2 c-frags). gl_lds staging,
// LDS stride 64. Epilogue: LDS roundtrip -> coalesced packed stores.
// Qp: ((((b*4+h)*128+qs)*2+ki)*64+lane)*8+j
// Kp: ((((((b*4+h)*32+kt)*2+half)*2+nj)*2+ki)*64+lane)*8+j
// Vp: ((((((b*4+h)*32+kt)*2+half)*4+ni)*2+w)*64+lane)*8+j
__global__ __launch_bounds__(512) void gemm_qkv_kernel(
    const u16* __restrict__ A, const u16* __restrict__ BT,
    u16* __restrict__ Qp, u16* __restrict__ Kp, u16* __restrict__ Vp,
    int Kdim) {
    __shared__ u16 sm[16896];           // 33 KB; staging uses [0,16384)
    u16* Asl = sm;                       // 128x64, stride 64
    u16* Bsl = sm + 8192;                // 128x64, stride 64
    const int tid = threadIdx.x;
    const int mbase = blockIdx.y * 128;
    const int nbase = blockIdx.x * 128;
    const int wave = tid >> 6, lane = tid & 63;
    const int wm = wave >> 2, wn = wave & 3;   // 2m x 4n
    const int lq = lane & 15, quad = lane >> 4;

    // staging: wave covers 16 rows of A and of B (2 issues of 8 rows each)
    const u16* gA = A + (size_t)(mbase + wave * 16 + (lane >> 3)) * Kdim + (lane & 7) * 8;
    const u16* gB = BT + (size_t)(nbase + wave * 16 + (lane >> 3)) * Kdim + (lane & 7) * 8;
    u16* lA = &Asl[(wave * 16) * 64];
    u16* lB = &Bsl[(wave * 16) * 64];

    const floatx4 z4 = {0.f, 0.f, 0.f, 0.f};
    floatx4 acc[4][2];
#pragma unroll
    for (int i = 0; i < 4; i++)
#pragma unroll
        for (int j = 0; j < 2; j++) acc[i][j] = z4;

    const int nk = Kdim >> 6;
    for (int kk = 0; kk < nk; kk++) {
        const int kb = kk << 6;
        if (kk) __syncthreads();
#pragma unroll
        for (int i = 0; i < 2; i++) {
            gload_lds16(gA + kb + (size_t)(i * 8) * Kdim, lA + (i * 8) * 64);
            gload_lds16(gB + kb + (size_t)(i * 8) * Kdim, lB + (i * 8) * 64);
        }
        __syncthreads();
#pragma unroll
        for (int ki = 0; ki < 2; ki++) {
            short8 af[4], bf[2];
#pragma unroll
            for (int mi = 0; mi < 4; mi++)
                af[mi] = *(const short8*)&Asl[(wm * 64 + mi * 16 + lq) * 64 + ki * 32 + quad * 8];
#pragma unroll
            for (int ni = 0; ni < 2; ni++)
                bf[ni] = *(const short8*)&Bsl[(wn * 32 + ni * 16 + lq) * 64 + ki * 32 + quad * 8];
#pragma unroll
            for (int mi = 0; mi < 4; mi++)
#pragma unroll
                for (int ni = 0; ni < 2; ni++)
                    acc[mi][ni] = MFMA16(af[mi], bf[ni], acc[mi][ni]);
        }
    }
    // ---- epilogue phase 1: C-tile -> sm (stride 132; V-tiles transposed).
    // C/D layout: col = wn*32+ni*16+lq, row = wm*64+mi*16+quad*4+r.
    __syncthreads();
    const bool vtile = (nbase >= 512);
#pragma unroll
    for (int mi = 0; mi < 4; mi++)
#pragma unroll
        for (int ni = 0; ni < 2; ni++) {
            int cl = wn * 32 + ni * 16 + lq;
#pragma unroll
            for (int r = 0; r < 4; r++) {
                int rl = wm * 64 + mi * 16 + quad * 4 + r;
                if (vtile) sm[cl * 132 + rl] = f2bf(acc[mi][ni][r]);  // transposed
                else       sm[rl * 132 + cl] = f2bf(acc[mi][ni][r]);
            }
        }
    __syncthreads();
    // ---- phase 2: 32 coalesced 1KB wave-lines (4 per wave). ----
    const int b = mbase >> 11;
    const int keyb = mbase & 2047;
    if (nbase < 256) {                        // Q tile
        const int hq = nbase >> 6;           // {0,2}
        const int qs_base = keyb >> 4;
#pragma unroll
        for (int t = 0; t < 4; t++) {
            int l = wave * 4 + t;
            int qs2 = l >> 2, h2 = (l >> 1) & 1, ki = l & 1;
            int qd = lane >> 4, lqq = lane & 15;
            short8 v = *(const short8*)&sm[(qs2 * 16 + lqq) * 132 + h2 * 64 + ki * 32 + qd * 8];
            int h = hq + h2;
            size_t base = ((size_t)(((b * 4 + h) * 128 + (qs_base + qs2)) * 2 + ki) * 64 + lane) << 3;
            *(short8*)&Qp[base] = v;
        }
    } else if (nbase < 512) {                 // K tile
        const int hb = (nbase - 256) >> 6;   // {0,2}
        const int ktb = keyb >> 6;
#pragma unroll
        for (int t = 0; t < 4; t++) {
            int l = wave * 4 + t;
            int kt2 = l >> 4, hf = (l >> 3) & 1, nj = (l >> 2) & 1;
            int h2 = (l >> 1) & 1, ki = l & 1;
            int quadk = lane >> 4, lqk = lane & 15;
            short8 v = *(const short8*)&sm[(kt2 * 64 + hf * 32 + lqk * 2 + nj) * 132 +
                                           h2 * 64 + ki * 32 + quadk * 8];
            int h = hb + h2;
            size_t base = ((size_t)(((((b * 4 + h) * 32 + (ktb + kt2)) * 2 + hf) * 2 + nj)
                                    * 2 + ki) * 64 + lane) << 3;
            *(short8*)&Kp[base] = v;
        }
    } else {                                  // V tile (sm transposed)
        const int h = (nbase - 512) >> 7;    // tile spans one head
        const int ktb = keyb >> 6;
#pragma unroll
        for (int t = 0; t < 4; t++) {
            int l = wave * 4 + t;
            int kt2 = l >> 4, hf = (l >> 3) & 1, niv = (l >> 1) & 3, wv = l & 1;
            int quadv = lane >> 4, lqv = lane & 15;
            short8 v = *(const short8*)&sm[(hf * 64 + niv * 16 + lqv) * 132 +
                                           kt2 * 64 + wv * 32 + quadv * 8];
            size_t base = ((size_t)(((((b * 4 + h) * 32 + (ktb + kt2)) * 2 + hf) * 4 + niv)
                                    * 2 + wv) * 64 + lane) << 3;
            *(short8*)&Vp[base] = v;
        }
    }
}

// ------- out GEMM: C[M][N] fp32 = A[M][K]*BT[N][K]^T, 64x128 tile, 512 thr
// 8 waves as 2m x 4n, each wave 32x32 (2x2 c-frags). grid (4, 128) = 512 WGs
// -> 2 WG/CU x 8 waves = 16 waves/CU. LDS: A 8KB + B 16KB.
__global__ __launch_bounds__(512) void gemm_out_kernel(
    const u16* __restrict__ A, const u16* __restrict__ BT,
    float* __restrict__ Cf, int Kdim, int ldc) {
    __shared__ u16 Asl[64 * 64];
    __shared__ u16 Bsl[128 * 64];
    const int tid = threadIdx.x;
    const int mbase = blockIdx.y * 64;
    const int nbase = blockIdx.x * 128;
    const int wave = tid >> 6, lane = tid & 63;
    const int wm = wave >> 2, wn = wave & 3;
    const int lq = lane & 15, quad = lane >> 4;

    const u16* gA = A + (size_t)(mbase + wave * 8 + (lane >> 3)) * Kdim + (lane & 7) * 8;
    const u16* gB = BT + (size_t)(nbase + wave * 16 + (lane >> 3)) * Kdim + (lane & 7) * 8;
    u16* lA = &Asl[(wave * 8) * 64];
    u16* lB = &Bsl[(wave * 16) * 64];

    const floatx4 z4 = {0.f, 0.f, 0.f, 0.f};
    floatx4 acc[2][2];
#pragma unroll
    for (int i = 0; i < 2; i++)
#pragma unroll
        for (int j = 0; j < 2; j++) acc[i][j] = z4;

    const int nk = Kdim >> 6;
    for (int kk = 0; kk < nk; kk++) {
        const int kb = kk << 6;
        if (kk) __syncthreads();
        gload_lds16(gA + kb, lA);
        gload_lds16(gB + kb, lB);
        gload_lds16(gB + kb + (size_t)8 * Kdim, lB + 8 * 64);
        __syncthreads();
#pragma unroll
        for (int ki = 0; ki < 2; ki++) {
            short8 af[2], bf[2];
#pragma unroll
            for (int mi = 0; mi < 2; mi++)
                af[mi] = *(const short8*)&Asl[(wm * 32 + mi * 16 + lq) * 64 + ki * 32 + quad * 8];
#pragma unroll
            for (int ni = 0; ni < 2; ni++)
                bf[ni] = *(const short8*)&Bsl[(wn * 32 + ni * 16 + lq) * 64 + ki * 32 + quad * 8];
#pragma unroll
            for (int mi = 0; mi < 2; mi++)
#pragma unroll
                for (int ni = 0; ni < 2; ni++)
                    acc[mi][ni] = MFMA16(af[mi], bf[ni], acc[mi][ni]);
        }
    }
#pragma unroll
    for (int mi = 0; mi < 2; mi++)
#pragma unroll
        for (int ni = 0; ni < 2; ni++)
#pragma unroll
            for (int r = 0; r < 4; r++)
                Cf[(size_t)(mbase + wm * 32 + mi * 16 + quad * 4 + r) * ldc +
                   (nbase + wn * 32 + ni * 16 + lq)] = acc[mi][ni][r];
}

// ---------------- fused attention (unchanged from R9) --------------------
__global__ __launch_bounds__(512) void attn_kernel(const u16* __restrict__ Qp,
                                                   const u16* __restrict__ Kp,
                                                   const u16* __restrict__ Vp,
                                                   u16* __restrict__ Pp) {
    __shared__ u16 pl[2 * 4 * 4096];  // [buf][mi][b*16+q][64], 64 KB exactly
    const int bx = blockIdx.x;
    const int h = bx & 3;
    const int ck = (bx >> 2) & 3;
    const int qt = bx >> 4;                     // [0,32)
    const int tid = threadIdx.x;
    const int wave = tid >> 6, lane = tid & 63;
    const int mi = wave & 3, half = wave >> 2;  // S phase roles
    const int dq = wave;                        // PV phase: dv-16-slice
    const int half_v = dq >> 2, ni_v = dq & 3;
    const int lq = lane & 15, quad = lane >> 4;
    const int qs = qt * 4 + mi;

    short8 aq[4][2];
#pragma unroll
    for (int b = 0; b < 4; b++)
#pragma unroll
        for (int ki = 0; ki < 2; ki++)
            aq[b][ki] = *(const short8*)&Qp[
                ((size_t)((((b * 4 + h) * 128 + qs) * 2 + ki) * 64 + lane) << 3)];

    const floatx4 z4 = {0.f, 0.f, 0.f, 0.f};
    floatx4 oacc[4][4];  // [b][m2]
#pragma unroll
    for (int b = 0; b < 4; b++)
#pragma unroll
        for (int m2 = 0; m2 < 4; m2++) oacc[b][m2] = z4;

    for (int kt = ck * 8; kt < ck * 8 + 8; kt++) {
        u16* plb = &pl[((kt & 1) * 4 + mi) * 4096];
        u16* plbuf = &pl[(kt & 1) * 4 * 4096];
        floatx4 s[4][2];
#pragma unroll
        for (int b = 0; b < 4; b++) {
            const u16* kb = Kp +
                ((size_t)((((b * 4 + h) * 32 + kt) * 2 + half) * 2) << 10) +
                lane * 8;
#pragma unroll
            for (int nj = 0; nj < 2; nj++) {
                s[b][nj] = z4;
#pragma unroll
                for (int ki = 0; ki < 2; ki++)
                    s[b][nj] = MFMA16(aq[b][ki],
                                      *(const short8*)(kb + (nj * 2 + ki) * 512),
                                      s[b][nj]);
            }
        }
        short8 vf[4][2];
#pragma unroll
        for (int b = 0; b < 4; b++) {
            const u16* vb = Vp +
                ((size_t)(((((b * 4 + h) * 32 + kt) * 2 + half_v) * 4 + ni_v) * 2) << 9) +
                lane * 8;
            vf[b][0] = *(const short8*)vb;
            vf[b][1] = *(const short8*)(vb + 512);
        }
#pragma unroll
        for (int r = 0; r < 4; r++) {
            float e0a = ex2(s[0][0][r]), e0b = ex2(s[0][1][r]);
            float e1a = ex2(s[1][0][r]), e1b = ex2(s[1][1][r]);
            float e2a = ex2(s[2][0][r]), e2b = ex2(s[2][1][r]);
            float e3a = ex2(s[3][0][r]), e3b = ex2(s[3][1][r]);
            float ia = __builtin_amdgcn_rcpf(e0a + e1a + e2a + e3a);
            float ib = __builtin_amdgcn_rcpf(e0b + e1b + e2b + e3b);
            int q = quad * 4 + r;
            int col = (half * 32 + 2 * lq) ^ ((q & 7) * 8);  // XOR swizzle
            *(u32*)&plb[(0 * 16 + q) * 64 + col] = pk2bf(e0a * ia, e0b * ib);
            *(u32*)&plb[(1 * 16 + q) * 64 + col] = pk2bf(e1a * ia, e1b * ib);
            *(u32*)&plb[(2 * 16 + q) * 64 + col] = pk2bf(e2a * ia, e2b * ib);
            *(u32*)&plb[(3 * 16 + q) * 64 + col] = pk2bf(e3a * ia, e3b * ib);
        }
        __syncthreads();
        const int sw = (lq & 7) * 8;
#pragma unroll
        for (int b = 0; b < 4; b++) {
#pragma unroll
            for (int m2 = 0; m2 < 4; m2++) {
                const u16* pm = plbuf + m2 * 4096;
                short8 ap0 = *(const short8*)&pm[(b * 16 + lq) * 64 + ((quad * 8) ^ sw)];
                short8 ap1 = *(const short8*)&pm[(b * 16 + lq) * 64 + ((32 + quad * 8) ^ sw)];
                oacc[b][m2] = MFMA16(ap0, vf[b][0], oacc[b][m2]);
                oacc[b][m2] = MFMA16(ap1, vf[b][1], oacc[b][m2]);
            }
        }
    }
    u16* Pc = Pp + (size_t)ck * (8192 * 512);
#pragma unroll
    for (int b = 0; b < 4; b++)
#pragma unroll
        for (int m2 = 0; m2 < 4; m2++)
#pragma unroll
            for (int r = 0; r < 4; r++)
                Pc[(size_t)(b * 2048 + qt * 64 + m2 * 16 + quad * 4 + r) * 512 +
                   h * 128 + dq * 16 + lq] = f2bf(oacc[b][m2][r]);
}

// ---------------- reduce 4 bf16 partials in place (P0 += P1+P2+P3) --------
__global__ __launch_bounds__(256) void reduce4_kernel(u16* __restrict__ P) {
    const size_t S = (size_t)8192 * 512;
    size_t i = ((size_t)blockIdx.x * 256 + threadIdx.x) * 8;  // 2048 blocks
    short8 a = *(short8*)&P[i];
    short8 b = *(short8*)&P[i + S];
    short8 c = *(short8*)&P[i + 2 * S];
    short8 d = *(short8*)&P[i + 3 * S];
    short8 o;
#pragma unroll
    for (int j = 0; j < 8; j++) {
        float s = bf2f((u16)a[j]) + bf2f((u16)b[j]) +
                  bf2f((u16)c[j]) + bf2f((u16)d[j]);
        o[j] = (short)f2bf(s);
    }
    *(short8*)&P[i] = o;
}

extern "C" void kernel_launch(void* const* d_in, const int* in_sizes, int n_in,
                              void* d_out, int out_size, void* d_ws, size_t ws_size,
                              hipStream_t stream) {
    const float* x  = (const float*)d_in[0];
    const float* Wq = (const float*)d_in[1];
    const float* Wk = (const float*)d_in[2];
    const float* Wv = (const float*)d_in[3];
    const float* Wo = (const float*)d_in[4];
    float* out = (float*)d_out;

    // Workspace map (48.5 MB). Pp[0..4) partials occupy [0, 32MB); Xb (8MB)
    // and WallT (1MB) are OVERLAID at the start -- both dead before attn
    // writes partials. P0 doubles as AO after reduce4.
    char* ws = (char*)d_ws;
    u16* Pp    = (u16*)ws;                                   // 4 x 8MB bf16
    u16* Xb    = (u16*)ws;                                   // overlay [0,8MB)
    u16* WallT = (u16*)(ws + (size_t)8 * 1024 * 1024);       // overlay [8,9MB)
    char* tail = ws + (size_t)32 * 1024 * 1024;
    u16* WoT   = (u16*)tail; tail += (size_t)512 * 512 * 2;  // 0.5MB
    u16* Qp    = (u16*)tail; tail += (size_t)8192 * 256 * 2; // 4MB
    u16* Kp    = (u16*)tail; tail += (size_t)8192 * 256 * 2; // 4MB
    u16* Vp    = (u16*)tail; tail += (size_t)8192 * 512 * 2; // 8MB

    prep_all_kernel<<<7168, 256, 0, stream>>>(x, Xb, Wq, Wk, Wv, Wo, WallT, WoT);
    // QKV = X @ [Wq|Wk|Wv] : [8192,1024] -> Qp/Kp/Vp packed (512 WGs, 512thr)
    gemm_qkv_kernel<<<dim3(8, 64), 512, 0, stream>>>(Xb, WallT, Qp, Kp, Vp, 512);
    attn_kernel<<<512, 512, 0, stream>>>(Qp, Kp, Vp, Pp);
    reduce4_kernel<<<2048, 256, 0, stream>>>(Pp);
    // out = AO(=P0) @ Wo : fp32 (512 WGs, 512thr, 64x128 tiles)
    gemm_out_kernel<<<dim3(4, 128), 512, 0, stream>>>(Pp, WoT, out, 512, 512);
}